// Round 1
// baseline (277.820 us; speedup 1.0000x reference)
//
#include <hip/hip_runtime.h>
#include <math.h>

#define BB 32
#define SS 2048
#define EE 6144
#define ET 128   // gemm e-tile
#define TJ 64    // gemm k-tile

// ---------------- stats of original x (ddof=1) + copy to xbuf ----------------
__global__ __launch_bounds__(256) void k_stats0(const float* __restrict__ x,
                                                float* __restrict__ xbuf,
                                                float* __restrict__ stats) {
  int b = blockIdx.x;
  const float* row = x + b * SS;
  float s = 0.f, s2 = 0.f;
  for (int j = threadIdx.x; j < SS; j += 256) {
    float v = row[j];
    xbuf[b * SS + j] = v;
    s += v; s2 += v * v;
  }
  __shared__ float sm[8];
  for (int off = 32; off; off >>= 1) { s += __shfl_down(s, off); s2 += __shfl_down(s2, off); }
  int lane = threadIdx.x & 63, wid = threadIdx.x >> 6;
  if (lane == 0) { sm[wid] = s; sm[4 + wid] = s2; }
  __syncthreads();
  if (threadIdx.x == 0) {
    float ts = sm[0] + sm[1] + sm[2] + sm[3];
    float ts2 = sm[4] + sm[5] + sm[6] + sm[7];
    float mu = ts / SS;
    float var = (ts2 - SS * mu * mu) / (SS - 1);
    stats[b] = mu;
    stats[BB + b] = var;
  }
}

// ---------------- LayerNorm (biased var, eps 1e-5) ----------------
__global__ __launch_bounds__(256) void k_layernorm(const float* __restrict__ x,
                                                   const float* __restrict__ g,
                                                   const float* __restrict__ be,
                                                   float* __restrict__ u) {
  int b = blockIdx.x;
  const float* row = x + b * SS;
  float s = 0.f, s2 = 0.f;
  for (int j = threadIdx.x; j < SS; j += 256) { float v = row[j]; s += v; s2 += v * v; }
  __shared__ float sm[8];
  __shared__ float smu, srs;
  for (int off = 32; off; off >>= 1) { s += __shfl_down(s, off); s2 += __shfl_down(s2, off); }
  int lane = threadIdx.x & 63, wid = threadIdx.x >> 6;
  if (lane == 0) { sm[wid] = s; sm[4 + wid] = s2; }
  __syncthreads();
  if (threadIdx.x == 0) {
    float ts = sm[0] + sm[1] + sm[2] + sm[3];
    float ts2 = sm[4] + sm[5] + sm[6] + sm[7];
    float mu = ts / SS;
    float var = ts2 / SS - mu * mu;
    smu = mu;
    srs = rsqrtf(var + 1e-5f);
  }
  __syncthreads();
  float mu = smu, rs = srs;
  for (int j = threadIdx.x; j < SS; j += 256) {
    float v = row[j];
    u[b * SS + j] = (v - mu) * rs * g[j] + be[j];
  }
}

// ---------------- attention core (head_dim=1), j-split x4 ----------------
// grid: (SS/64, BB); block 256.  tid&63 = local i, tid>>6 = j-quarter.
__global__ __launch_bounds__(256) void k_attn(const float* __restrict__ u,
                                              float* __restrict__ xbuf,
                                              const float* __restrict__ ipw,
                                              const float* __restrict__ ipb,
                                              const float* __restrict__ owp,
                                              const float* __restrict__ obp) {
  int b = blockIdx.y;
  __shared__ float2 kv[SS];
  __shared__ float red[8];
  __shared__ float skmax, skmin;
  __shared__ float ssum[3][64], tsum[3][64];
  float wq = ipw[0], wk = ipw[1], wv = ipw[2];
  float bq = ipb[0], bk = ipb[1], bv = ipb[2];
  const float* urow = u + b * SS;
  float kmax = -1e30f, kmin = 1e30f;
  for (int j = threadIdx.x; j < SS; j += 256) {
    float uu = urow[j];
    float kj = fmaf(uu, wk, bk);
    float vj = fmaf(uu, wv, bv);
    kv[j] = make_float2(kj, vj);
    kmax = fmaxf(kmax, kj);
    kmin = fminf(kmin, kj);
  }
  for (int off = 32; off; off >>= 1) {
    kmax = fmaxf(kmax, __shfl_down(kmax, off));
    kmin = fminf(kmin, __shfl_down(kmin, off));
  }
  int lane = threadIdx.x & 63, wid = threadIdx.x >> 6;
  if (lane == 0) { red[wid] = kmax; red[4 + wid] = kmin; }
  __syncthreads();
  if (threadIdx.x == 0) {
    skmax = fmaxf(fmaxf(red[0], red[1]), fmaxf(red[2], red[3]));
    skmin = fminf(fminf(red[4], red[5]), fminf(red[6], red[7]));
  }
  __syncthreads();
  kmax = skmax; kmin = skmin;
  int il = threadIdx.x & 63;
  int jq = threadIdx.x >> 6;
  int i = blockIdx.x * 64 + il;
  float q = fmaf(urow[i], wq, bq);
  float m = fmaxf(q * kmax, q * kmin);  // true row max of q*k_j
  float s = 0.f, t = 0.f;
  int j0 = jq * 512;
#pragma unroll 4
  for (int j = j0; j < j0 + 512; j++) {
    float2 c = kv[j];
    float e = __expf(fmaf(q, c.x, -m));
    s += e;
    t = fmaf(e, c.y, t);
  }
  if (jq) { ssum[jq - 1][il] = s; tsum[jq - 1][il] = t; }
  __syncthreads();
  if (jq == 0) {
    s += ssum[0][il] + ssum[1][il] + ssum[2][il];
    t += tsum[0][il] + tsum[1][il] + tsum[2][il];
    float o = t / s;
    xbuf[b * SS + i] += fmaf(o, owp[0], obp[0]);
  }
}

// ---------------- skinny GEMM partials: part[ks][b][n] = A[32][K] @ W[N][K]^T slice ----------------
// grid: (N/ET, KS); block 256.  Thread: b in {4*tb..+3}, e in {te, te+32, te+64, te+96}.
__global__ __launch_bounds__(256) void k_gemm_part(const float* __restrict__ A,
                                                   const float* __restrict__ W,
                                                   float* __restrict__ part,
                                                   int K, int N, int krange) {
  __shared__ float lw[ET][TJ + 1];
  __shared__ float lu[BB][TJ + 1];
  int e0 = blockIdx.x * ET;
  int kbase = blockIdx.y * krange;
  int tid = threadIdx.x;
  int te = tid & 31;
  int tb = tid >> 5;
  float acc[4][4];
#pragma unroll
  for (int p = 0; p < 4; p++)
#pragma unroll
    for (int q = 0; q < 4; q++) acc[p][q] = 0.f;

  for (int kt = 0; kt < krange; kt += TJ) {
    int j0 = kbase + kt;
    __syncthreads();
    // stage A tile (32 x 64), coalesced
    for (int idx = tid; idx < BB * TJ; idx += 256) {
      int bb = idx >> 6, jj = idx & 63;
      lu[bb][jj] = A[(size_t)bb * K + j0 + jj];
    }
    // stage W tile (128 x 64) via float4, coalesced
    for (int idx = tid; idx < ET * (TJ / 4); idx += 256) {
      int ee = idx >> 4, j4 = (idx & 15) * 4;
      const float4 w4 = *reinterpret_cast<const float4*>(&W[(size_t)(e0 + ee) * K + j0 + j4]);
      lw[ee][j4] = w4.x; lw[ee][j4 + 1] = w4.y; lw[ee][j4 + 2] = w4.z; lw[ee][j4 + 3] = w4.w;
    }
    __syncthreads();
#pragma unroll 8
    for (int jj = 0; jj < TJ; jj++) {
      float a0 = lu[4 * tb + 0][jj];
      float a1 = lu[4 * tb + 1][jj];
      float a2 = lu[4 * tb + 2][jj];
      float a3 = lu[4 * tb + 3][jj];
      float w0 = lw[te][jj];
      float w1 = lw[te + 32][jj];
      float w2 = lw[te + 64][jj];
      float w3 = lw[te + 96][jj];
      acc[0][0] = fmaf(a0, w0, acc[0][0]); acc[0][1] = fmaf(a0, w1, acc[0][1]);
      acc[0][2] = fmaf(a0, w2, acc[0][2]); acc[0][3] = fmaf(a0, w3, acc[0][3]);
      acc[1][0] = fmaf(a1, w0, acc[1][0]); acc[1][1] = fmaf(a1, w1, acc[1][1]);
      acc[1][2] = fmaf(a1, w2, acc[1][2]); acc[1][3] = fmaf(a1, w3, acc[1][3]);
      acc[2][0] = fmaf(a2, w0, acc[2][0]); acc[2][1] = fmaf(a2, w1, acc[2][1]);
      acc[2][2] = fmaf(a2, w2, acc[2][2]); acc[2][3] = fmaf(a2, w3, acc[2][3]);
      acc[3][0] = fmaf(a3, w0, acc[3][0]); acc[3][1] = fmaf(a3, w1, acc[3][1]);
      acc[3][2] = fmaf(a3, w2, acc[3][2]); acc[3][3] = fmaf(a3, w3, acc[3][3]);
    }
  }
  float* out = part + (size_t)blockIdx.y * BB * N;
#pragma unroll
  for (int p = 0; p < 4; p++) {
    int bb = 4 * tb + p;
#pragma unroll
    for (int q = 0; q < 4; q++) {
      out[(size_t)bb * N + e0 + te + 32 * q] = acc[p][q];
    }
  }
}

// ---------------- reduce K-split partials: gemm1 (bias + leakyrelu -> h) ----------------
__global__ __launch_bounds__(256) void k_reduce1(const float* __restrict__ part,
                                                 const float* __restrict__ b1,
                                                 float* __restrict__ h) {
  int idx = blockIdx.x * 256 + threadIdx.x;
  if (idx >= BB * EE) return;
  float s = 0.f;
#pragma unroll
  for (int ks = 0; ks < 8; ks++) s += part[(size_t)ks * (BB * EE) + idx];
  int e = idx % EE;
  s += b1[e];
  h[idx] = s >= 0.f ? s : 0.5f * s;
}

// ---------------- reduce K-split partials: gemm2 (bias + residual into xbuf) ----------------
__global__ __launch_bounds__(256) void k_reduce2(const float* __restrict__ part,
                                                 const float* __restrict__ b2,
                                                 float* __restrict__ xbuf) {
  int idx = blockIdx.x * 256 + threadIdx.x;
  if (idx >= BB * SS) return;
  float s = 0.f;
#pragma unroll
  for (int ks = 0; ks < 16; ks++) s += part[(size_t)ks * (BB * SS) + idx];
  s += b2[idx & (SS - 1)];
  xbuf[idx] += s;
}

// ---------------- final renorm to original mean/var ----------------
__global__ __launch_bounds__(256) void k_final(const float* __restrict__ xbuf,
                                               const float* __restrict__ stats,
                                               float* __restrict__ out) {
  int b = blockIdx.x;
  const float* row = xbuf + b * SS;
  float s = 0.f, s2 = 0.f;
  for (int j = threadIdx.x; j < SS; j += 256) { float v = row[j]; s += v; s2 += v * v; }
  __shared__ float sm[8];
  __shared__ float smu, srs;
  for (int off = 32; off; off >>= 1) { s += __shfl_down(s, off); s2 += __shfl_down(s2, off); }
  int lane = threadIdx.x & 63, wid = threadIdx.x >> 6;
  if (lane == 0) { sm[wid] = s; sm[4 + wid] = s2; }
  __syncthreads();
  if (threadIdx.x == 0) {
    float ts = sm[0] + sm[1] + sm[2] + sm[3];
    float ts2 = sm[4] + sm[5] + sm[6] + sm[7];
    float mu = ts / SS;
    float var = (ts2 - SS * mu * mu) / (SS - 1);
    smu = mu;
    srs = rsqrtf(var + 2.220446049250313e-16f);
  }
  __syncthreads();
  float mu = smu, rs = srs;
  float scale = sqrtf(stats[BB + b] + 2.220446049250313e-16f);
  float mean0 = stats[b];
  for (int j = threadIdx.x; j < SS; j += 256) {
    out[b * SS + j] = (row[j] - mu) * rs * scale + mean0;
  }
}

extern "C" void kernel_launch(void* const* d_in, const int* in_sizes, int n_in,
                              void* d_out, int out_size, void* d_ws, size_t ws_size,
                              hipStream_t stream) {
  const float* x         = (const float*)d_in[0];
  const float* attn_ln_g = (const float*)d_in[1];
  const float* attn_ln_b = (const float*)d_in[2];
  const float* ipw       = (const float*)d_in[3];   // [2][3]
  const float* ipb       = (const float*)d_in[4];   // [2][3]
  const float* out_w     = (const float*)d_in[5];   // [2]
  const float* out_b     = (const float*)d_in[6];   // [2]
  const float* mlp_ln_g  = (const float*)d_in[7];
  const float* mlp_ln_b  = (const float*)d_in[8];
  const float* W1        = (const float*)d_in[9];   // [2][E][S]
  const float* b1        = (const float*)d_in[10];  // [2][E]
  const float* W2        = (const float*)d_in[11];  // [2][S][E]
  const float* b2        = (const float*)d_in[12];  // [2][S]

  float* ws    = (float*)d_ws;
  float* xbuf  = ws;                       // 65536
  float* u     = xbuf + BB * SS;           // 65536
  float* h     = u + BB * SS;              // 196608
  float* part  = h + BB * EE;              // max(8*196608, 16*65536) = 1572864
  float* stats = part + 8 * BB * EE;       // 64

  k_stats0<<<BB, 256, 0, stream>>>(x, xbuf, stats);

  for (int l = 0; l < 2; l++) {
    // ---- attention block ----
    k_layernorm<<<BB, 256, 0, stream>>>(xbuf, attn_ln_g + l * SS, attn_ln_b + l * SS, u);
    k_attn<<<dim3(SS / 64, BB), 256, 0, stream>>>(u, xbuf, ipw + l * 3, ipb + l * 3,
                                                  out_w + l, out_b + l);
    // ---- MLP block ----
    k_layernorm<<<BB, 256, 0, stream>>>(xbuf, mlp_ln_g + l * SS, mlp_ln_b + l * SS, u);
    k_gemm_part<<<dim3(EE / ET, 8), 256, 0, stream>>>(u, W1 + (size_t)l * EE * SS, part,
                                                      SS, EE, SS / 8);
    k_reduce1<<<(BB * EE + 255) / 256, 256, 0, stream>>>(part, b1 + (size_t)l * EE, h);
    k_gemm_part<<<dim3(SS / ET, 16), 256, 0, stream>>>(h, W2 + (size_t)l * SS * EE, part,
                                                       EE, SS, EE / 16);
    k_reduce2<<<(BB * SS + 255) / 256, 256, 0, stream>>>(part, b2 + (size_t)l * SS, xbuf);
  }

  k_final<<<BB, 256, 0, stream>>>(xbuf, stats, (float*)d_out);
}